// Round 18
// baseline (148.242 us; speedup 1.0000x reference)
//
#include <hip/hip_runtime.h>

// ---------------------------------------------------------------------------
// Split Sparse-MMoE forward for MI355X (gfx950), v18.
// B=65536, D=512, E=8, H1=64, H2=32, O=64, T=2, K=2.
//
// v18 = four kernels, each individually proven or trivially safe:
//   prep    : weight repack (unchanged).
//   convert : x fp32 -> bf16 xbf image, SINGLE-consumer streaming kernel
//             (fixes r11/r17's dual-consumer register collapse). 1KB fully
//             coalesced stores: xbf[b][kq16][p4][tok64][16B].
//   gate    : r10 verbatim (proven ~19us) - routing + imp/load + loss.
//   main    : r17's expert kernel (proven ~27us, correct) with the DMA
//             source formula matched to the new xbf layout.
// Fallback (ws too small): XBF=0 = r10 verbatim.
// ---------------------------------------------------------------------------

typedef short bfrag __attribute__((ext_vector_type(8)));   // 8 bf16 = 4 VGPRs
typedef float facc  __attribute__((ext_vector_type(4)));   // 4 f32 accum

#define MFMA16(a, b, c) __builtin_amdgcn_mfma_f32_16x16x32_bf16((a), (b), (c), 0, 0, 0)

typedef const __attribute__((address_space(1))) unsigned int guint;
typedef __attribute__((address_space(3))) unsigned int luint;

__device__ __forceinline__ unsigned short bfbits(float f) {
  unsigned int u = __builtin_bit_cast(unsigned int, f);
  u += 0x7FFFu + ((u >> 16) & 1u);          // RNE
  return (unsigned short)(u >> 16);
}
__device__ __forceinline__ unsigned pack2(float a, float b) {
  return (unsigned)bfbits(a) | ((unsigned)bfbits(b) << 16);
}
__device__ __forceinline__ float bf2f(unsigned short s) {
  unsigned int u = ((unsigned int)s) << 16;
  return __builtin_bit_cast(float, u);
}

// ============================ convert kernel ===============================
// 1024 blocks x 1024 thr; b covers 64 tokens. Thread (kq=tid>>6, tok=tid&63)
// holds x[tok, kq*32 .. +32).  xbf element (b, tok, k) lives at
//   b*65536 + (k>>5)*4096 + ((k&31)>>3)*1024 + tok*16 + (k&7)*2
// so thread writes 4x16B at b*65536 + kq*4096 + p*1024 + tok*16 - within a
// wave kq is constant, tok = lane -> 64x16B contiguous (1KB) per store.
__global__ __launch_bounds__(1024) void moe_convert(
    const float* __restrict__ x, char* __restrict__ xbf)
{
  const int tid = threadIdx.x;
  const int kq = tid >> 6, tok = tid & 63;
  const float4* src = (const float4*)(x + (size_t)blockIdx.x * 32768 + tok * 512 + kq * 32);
  char* dst = xbf + (size_t)blockIdx.x * 65536 + kq * 4096 + tok * 16;
  #pragma unroll
  for (int p = 0; p < 4; ++p) {
    float4 f0 = src[2 * p];
    float4 f1 = src[2 * p + 1];
    uint4 v;
    v.x = pack2(f0.x, f0.y);
    v.y = pack2(f0.z, f0.w);
    v.z = pack2(f1.x, f1.y);
    v.w = pack2(f1.z, f1.w);
    *(uint4*)(dst + p * 1024) = v;
  }
}

// ============================ gating kernel (r10 verbatim) =================
// LDS: partials [16w][64tok][16te] f32 = 64K; G [64][20] f32 = 5120; lacc 128.
#define GG_OFF   65536
#define GL_OFF   70656
#define GSM_SIZE 70784

__global__ __launch_bounds__(1024, 4) void moe_gate(
    const float* __restrict__ x,
    const float* __restrict__ b_gates,
    const float* __restrict__ wgt,      // [16 te][512 k] f32, te = t*8+e
    float4* __restrict__ routing,       // [B][2 task] {g1,g2,e1,e2}
    float* __restrict__ gacc,           // [32] + cnt at word 32
    float* __restrict__ y)              // loss -> y[8388608]
{
  __shared__ alignas(16) char gsm[GSM_SIZE];
  const int tid = threadIdx.x;
  const int wave = tid >> 6, lane = tid & 63;

  const float* src = x + (size_t)blockIdx.x * 64 * 512 + lane * 512 + wave * 32;
  float4 fr[8];
  #pragma unroll
  for (int j = 0; j < 8; ++j) fr[j] = ((const float4*)src)[j];

  if (tid < 32) ((float*)(gsm + GL_OFF))[tid] = 0.f;

  // exact fp32 partial dots, wave-uniform scalar weights
  {
    int wu = __builtin_amdgcn_readfirstlane(wave);
    const float* wbase = wgt + wu * 32;
    float* pp = (float*)(gsm + wave * 4096 + lane * 64);
    #pragma unroll
    for (int te = 0; te < 16; ++te) {
      const float* wrow = wbase + te * 512;
      float a0 = 0.f, a1 = 0.f, a2 = 0.f, a3 = 0.f;
      #pragma unroll
      for (int j = 0; j < 8; ++j) {
        a0 = fmaf(fr[j].x, wrow[j * 4 + 0], a0);
        a1 = fmaf(fr[j].y, wrow[j * 4 + 1], a1);
        a2 = fmaf(fr[j].z, wrow[j * 4 + 2], a2);
        a3 = fmaf(fr[j].w, wrow[j * 4 + 3], a3);
      }
      pp[(te + lane) & 15] = (a0 + a1) + (a2 + a3);   // te-rotation: conflict-free
    }
  }
  __syncthreads();

  // reduce 16 wave-partials -> logits
  {
    int tok = tid >> 4, te = tid & 15;
    const char* pb = gsm + tok * 64 + (((te + tok) & 15) * 4);
    float s = 0.f;
    #pragma unroll
    for (int w2 = 0; w2 < 16; ++w2) s += *(const float*)(pb + w2 * 4096);
    ((float*)(gsm + GG_OFF))[tok * 20 + te] = s + b_gates[te];
  }
  __syncthreads();

  // top-2 + softmax -> routing + local imp/load accum
  if (tid < 128) {
    int tok = tid >> 1, task = tid & 1;
    const float* Gr = (const float*)(gsm + GG_OFF) + tok * 20 + task * 8;
    float l[8];
    #pragma unroll
    for (int ee = 0; ee < 8; ++ee) l[ee] = Gr[ee];
    float v1 = l[0]; int e1 = 0;
    #pragma unroll
    for (int ee = 1; ee < 8; ++ee) { if (l[ee] > v1) { v1 = l[ee]; e1 = ee; } }
    float v2 = -3.4e38f; int e2 = 0;
    #pragma unroll
    for (int ee = 0; ee < 8; ++ee) {
      if (ee != e1 && l[ee] > v2) { v2 = l[ee]; e2 = ee; }
    }
    float g1 = 1.f / (1.f + __expf(v2 - v1));
    float g2 = 1.f - g1;
    float4 rec;
    rec.x = g1; rec.y = g2;
    rec.z = __int_as_float(e1); rec.w = __int_as_float(e2);
    routing[((size_t)blockIdx.x * 64 + tok) * 2 + task] = rec;
    float* lacc = (float*)(gsm + GL_OFF);
    atomicAdd(lacc + task * 8 + e1, g1);
    atomicAdd(lacc + task * 8 + e2, g2);
    atomicAdd(lacc + 16 + task * 8 + e1, 1.f);
    atomicAdd(lacc + 16 + task * 8 + e2, 1.f);
  }
  __syncthreads();
  if (tid < 32) atomicAdd(gacc + tid, ((float*)(gsm + GL_OFF))[tid]);
  __syncthreads();

  // last-block-done: cv^2 loss
  if (tid == 0) {
    __threadfence();
    unsigned* cnt = (unsigned*)(gacc + 32);
    unsigned old = atomicAdd(cnt, 1u);
    if (old == gridDim.x - 1) {
      float loss = 0.f;
      #pragma unroll
      for (int a = 0; a < 4; ++a) {      // [imp t0][imp t1][load t0][load t1]
        float v[8]; float mm = 0.f;
        #pragma unroll
        for (int i = 0; i < 8; ++i) {
          v[i] = __hip_atomic_load(gacc + a * 8 + i, __ATOMIC_RELAXED,
                                   __HIP_MEMORY_SCOPE_AGENT);
          mm += v[i];
        }
        mm *= 0.125f;
        float var = 0.f;
        #pragma unroll
        for (int i = 0; i < 8; ++i) { float d = v[i] - mm; var += d * d; }
        loss += (var * (1.f / 7.f)) / (mm * mm + 1e-10f);
      }
      y[8388608] = 0.01f * loss;
    }
  }
}

// ============================ main expert kernel ===========================
// LDS 32 KB: X tile [32 tok][512] bf16 pitch 1024, byte ^= ((tok&7)<<4).
// XBF staging: DMA 4x16B/thread; LDS dest linear; per-lane GLOBAL source
// does the layout inversion:
//   lin = off ^ (((off>>10)&7)<<4); tok = lin>>10; k0 = (lin&1023)>>1;
//   src = gbase + (k0>>5)*4096 + ((k0&31)>>3)*1024 + (glb+tok)*16
// where gbase = xbf + (blk>>1)*65536, glb = (blk&1)*32.
// After B1 reused as 8 expert chunks of 4 KB (H1 sigma -> H2 sigma2 -> Out).
template <int XBF>
__global__ __launch_bounds__(512, 6) void moe_main(
    const float* __restrict__ x,
    const char* __restrict__ xbf,
    const float* __restrict__ b1,
    const float* __restrict__ b2,
    const float* __restrict__ b3,
    const bfrag* __restrict__ w1f,
    const bfrag* __restrict__ w2f,
    const bfrag* __restrict__ w3f,
    const float4* __restrict__ routing,
    float* __restrict__ y)
{
  __shared__ alignas(16) char smem[32768];
  const int tid = threadIdx.x;
  const int wave = tid >> 6, lane = tid & 63;
  const int q = lane & 15, g = lane >> 4;
  const int e = wave;                       // 8 waves = 8 experts
  const unsigned cb = (unsigned)e * 4096u;  // own chunk

  // ---------------- stage X tile ----------------
  if (XBF) {
    const char* gbase = xbf + (size_t)(blockIdx.x >> 1) * 65536;
    const unsigned glb = ((unsigned)blockIdx.x & 1u) * 32u;
    #pragma unroll
    for (int it = 0; it < 4; ++it) {
      unsigned off = (unsigned)(it * 8192 + tid * 16);
      unsigned lin = off ^ (((off >> 10) & 7u) << 4);
      unsigned tok = lin >> 10;
      unsigned k0  = (lin & 1023u) >> 1;
      unsigned srcoff = (k0 >> 5) * 4096u + ((k0 & 31u) >> 3) * 1024u + (glb + tok) * 16u;
      __builtin_amdgcn_global_load_lds((guint*)(gbase + srcoff),
                                       (luint*)(smem + off), 16, 0, 0);
    }
  } else {
    const float* xblk = x + (size_t)blockIdx.x * 32 * 512;
    #pragma unroll 4
    for (int it = 0; it < 8; ++it) {
      int idx = it * 2048 + tid * 4;
      float4 v = *(const float4*)(xblk + idx);
      int r = idx >> 9, c = idx & 511;
      unsigned byte = ((unsigned)(r * 1024 + c * 2)) ^ ((unsigned)(r & 7) << 4);
      uint2 p; p.x = pack2(v.x, v.y); p.y = pack2(v.z, v.w);
      *(uint2*)(smem + byte) = p;
    }
  }
  __syncthreads();                                   // B0: X staged

  // ---------------- GEMM1: 32 tok x 64 h1, K=512 ----------------
  facc acc[2][4];
  #pragma unroll
  for (int m = 0; m < 2; ++m)
    #pragma unroll
    for (int n = 0; n < 4; ++n) acc[m][n] = (facc)0.f;

  const bfrag* w1e = w1f + e * 4096 + lane;
  #pragma unroll
  for (int ks = 0; ks < 16; ++ks) {
    bfrag B0 = w1e[ks * 256];
    bfrag B1 = w1e[ks * 256 + 64];
    bfrag B2 = w1e[ks * 256 + 128];
    bfrag B3 = w1e[ks * 256 + 192];
    #pragma unroll
    for (int m = 0; m < 2; ++m) {
      unsigned ba = ((unsigned)((m * 16 + q) * 1024 + ks * 64 + g * 16)) ^ ((unsigned)(q & 7) << 4);
      bfrag A = *(const bfrag*)(smem + ba);
      acc[m][0] = MFMA16(A, B0, acc[m][0]);
      acc[m][1] = MFMA16(A, B1, acc[m][1]);
      acc[m][2] = MFMA16(A, B2, acc[m][2]);
      acc[m][3] = MFMA16(A, B3, acc[m][3]);
    }
  }

  // preload GEMM2 weights + bias (in flight across barrier + H1 phase)
  bfrag W2r[4];
  #pragma unroll
  for (int i = 0; i < 4; ++i) W2r[i] = w2f[e * 256 + i * 64 + lane];
  float b2v0 = b2[e * 32 + q];
  float b2v1 = b2[e * 32 + 16 + q];
  __syncthreads();                                   // B1: X dead

  // ---------------- H1 -> own chunk (sigma: s = q*4+n) ----------------
  {
    float bv[4];
    #pragma unroll
    for (int n = 0; n < 4; ++n) bv[n] = b1[e * 64 + n * 16 + q];
    #pragma unroll
    for (int m = 0; m < 2; ++m) {
      #pragma unroll
      for (int j = 0; j < 4; ++j) {
        float v0 = fmaxf(acc[m][0][j] + bv[0], 0.f);
        float v1 = fmaxf(acc[m][1][j] + bv[1], 0.f);
        float v2 = fmaxf(acc[m][2][j] + bv[2], 0.f);
        float v3 = fmaxf(acc[m][3][j] + bv[3], 0.f);
        int rr = m * 16 + g * 4 + j;
        unsigned byte = cb + (((unsigned)(rr * 128 + q * 8)) ^ ((unsigned)(rr & 7) << 4));
        uint2 pk; pk.x = pack2(v0, v1); pk.y = pack2(v2, v3);
        *(uint2*)(smem + byte) = pk;
      }
    }
  }

  // ---------------- GEMM2: K=64 (sigma), N=32 ----------------
  {
    facc a2[2][2];
    #pragma unroll
    for (int m = 0; m < 2; ++m) { a2[m][0] = (facc)0.f; a2[m][1] = (facc)0.f; }
    #pragma unroll
    for (int ks = 0; ks < 2; ++ks) {
      #pragma unroll
      for (int m = 0; m < 2; ++m) {
        unsigned ba = cb + (((unsigned)((m * 16 + q) * 128 + ks * 64 + g * 16)) ^ ((unsigned)(q & 7) << 4));
        bfrag A = *(const bfrag*)(smem + ba);
        a2[m][0] = MFMA16(A, W2r[ks * 2], a2[m][0]);
        a2[m][1] = MFMA16(A, W2r[ks * 2 + 1], a2[m][1]);
      }
    }
    // preload GEMM3 weights + bias
    bfrag W3r[4];
    #pragma unroll
    for (int n = 0; n < 4; ++n) W3r[n] = w3f[e * 256 + n * 64 + lane];
    float b3v[4];
    #pragma unroll
    for (int n = 0; n < 4; ++n) b3v[n] = b3[e * 64 + n * 16 + q];

    // H2 -> own chunk front (sigma2: s = q*2+n)
    #pragma unroll
    for (int m = 0; m < 2; ++m) {
      #pragma unroll
      for (int j = 0; j < 4; ++j) {
        float v0 = fmaxf(a2[m][0][j] + b2v0, 0.f);
        float v1 = fmaxf(a2[m][1][j] + b2v1, 0.f);
        int rr = m * 16 + g * 4 + j;
        unsigned byte = cb + (((unsigned)(rr * 64 + q * 4)) ^ ((unsigned)(rr & 7) << 4));
        *(unsigned int*)(smem + byte) = pack2(v0, v1);
      }
    }

    // ---------------- GEMM3: K=32 (sigma2), N=64 ----------------
    facc a3[2][4];
    #pragma unroll
    for (int m = 0; m < 2; ++m)
      #pragma unroll
      for (int n = 0; n < 4; ++n) a3[m][n] = (facc)0.f;
    #pragma unroll
    for (int m = 0; m < 2; ++m) {
      unsigned ba = cb + (((unsigned)((m * 16 + q) * 64 + g * 16)) ^ ((unsigned)(q & 7) << 4));
      bfrag A = *(const bfrag*)(smem + ba);
      #pragma unroll
      for (int n = 0; n < 4; ++n) a3[m][n] = MFMA16(A, W3r[n], a3[m][n]);
    }
    // Out -> full own chunk (sigma: s = q*4+n), after all H2 reads (in-order)
    #pragma unroll
    for (int m = 0; m < 2; ++m) {
      #pragma unroll
      for (int j = 0; j < 4; ++j) {
        float v0 = fmaxf(a3[m][0][j] + b3v[0], 0.f);
        float v1 = fmaxf(a3[m][1][j] + b3v[1], 0.f);
        float v2 = fmaxf(a3[m][2][j] + b3v[2], 0.f);
        float v3 = fmaxf(a3[m][3][j] + b3v[3], 0.f);
        int rr = m * 16 + g * 4 + j;
        unsigned byte = cb + (((unsigned)(rr * 128 + q * 8)) ^ ((unsigned)(rr & 7) << 4));
        uint2 pk; pk.x = pack2(v0, v1); pk.y = pack2(v2, v3);
        *(uint2*)(smem + byte) = pk;
      }
    }
  }
  __syncthreads();                                   // B2: chunks complete

  // ---------------- combine: routing recs + weighted sum ----------------
  {
    int tok = tid >> 4, u = tid & 15;
    size_t trow = (size_t)blockIdx.x * 32 + tok;
    unsigned obyte = ((unsigned)(tok * 128 + u * 8)) ^ ((unsigned)(tok & 7) << 4);
    #pragma unroll
    for (int tt = 0; tt < 2; ++tt) {
      float4 rec = routing[trow * 2 + tt];
      float g1 = rec.x, g2 = rec.y;
      int e1 = __float_as_int(rec.z), e2 = __float_as_int(rec.w);
      uint2 o1 = *(const uint2*)(smem + e1 * 4096 + obyte);
      uint2 o2 = *(const uint2*)(smem + e2 * 4096 + obyte);
      unsigned short s1[4] = { (unsigned short)o1.x, (unsigned short)(o1.x >> 16),
                               (unsigned short)o1.y, (unsigned short)(o1.y >> 16) };
      unsigned short s2[4] = { (unsigned short)o2.x, (unsigned short)(o2.x >> 16),
                               (unsigned short)o2.y, (unsigned short)(o2.y >> 16) };
      float* yt = y + (size_t)tt * 4194304 + trow * 64;
      #pragma unroll
      for (int w = 0; w < 4; ++w) {
        // storage col s = 4u+w -> actual col c = w*16 + u
        yt[w * 16 + u] = g1 * bf2f(s1[w]) + g2 * bf2f(s2[w]);
      }
    }
  }
}

// ============================ weight repack ================================
//  w1f: [E][16ks][4n][64lane]       B = W1[k][h], h = n*16+q
//  w2f: [E][2ks][2n][64]            K in H1-sigma order: h = (s&3)*16 + (s>>2)
//  w3f: [E][1][4n][64]              K in H2-sigma order: h = (s&1)*16 + (s>>1)
//  wgt: [16 te][512 k] f32          te = t*8+e (exact copy for fp32 gating)
//  also zeroes gacc[32] + done-counter
__global__ __launch_bounds__(256) void moe_prep(
    const float* __restrict__ W1, const float* __restrict__ W2,
    const float* __restrict__ W3, const float* __restrict__ wg,
    bfrag* __restrict__ w1f, bfrag* __restrict__ w2f,
    bfrag* __restrict__ w3f, float* __restrict__ wgt,
    float* __restrict__ gacc)
{
  int tid = blockIdx.x * 256 + threadIdx.x;
  bfrag o;
  if (tid < 32768) {
    int lane = tid & 63, nt = (tid >> 6) & 3, ks = (tid >> 8) & 15, e = tid >> 12;
    int q = lane & 15, g = lane >> 4;
    int hcol = nt * 16 + q;
    #pragma unroll
    for (int j = 0; j < 8; ++j) {
      int k = ks * 32 + g * 8 + j;
      o[j] = (short)bfbits(W1[((e * 512 + k) * 64) + hcol]);
    }
    w1f[tid] = o;
  } else if (tid < 34816) {
    int idx = tid - 32768;
    int lane = idx & 63, nt = (idx >> 6) & 1, ks = (idx >> 7) & 1, e = idx >> 8;
    int q = lane & 15, g = lane >> 4;
    int n = nt * 16 + q;
    #pragma unroll
    for (int j = 0; j < 8; ++j) {
      int s = ks * 32 + g * 8 + j;
      int hh = (s & 3) * 16 + (s >> 2);
      o[j] = (short)bfbits(W2[(e * 64 + hh) * 32 + n]);
    }
    w2f[idx] = o;
  } else if (tid < 36864) {
    int idx = tid - 34816;
    int lane = idx & 63, nt = (idx >> 6) & 3, e = idx >> 8;
    int q = lane & 15, g = lane >> 4;
    int ocol = nt * 16 + q;
    #pragma unroll
    for (int j = 0; j < 8; ++j) {
      int s = g * 8 + j;
      int hh = (s & 1) * 16 + (s >> 1);
      o[j] = (short)bfbits(W3[(e * 32 + hh) * 64 + ocol]);
    }
    w3f[idx] = o;
  } else if (tid < 45056) {
    int idx = tid - 36864;            // te = idx>>9, k = idx&511
    int te = idx >> 9, k = idx & 511;
    wgt[idx] = wg[(((te >> 3) * 512) + k) * 8 + (te & 7)];
  } else if (tid < 45089) {
    gacc[tid - 45056] = 0.f;          // gacc[0..31] + cnt (word 32)
  }
}

extern "C" void kernel_launch(void* const* d_in, const int* in_sizes, int n_in,
                              void* d_out, int out_size, void* d_ws, size_t ws_size,
                              hipStream_t stream) {
  const float* x  = (const float*)d_in[0];
  const float* wg = (const float*)d_in[1];
  const float* bg = (const float*)d_in[2];
  const float* W1 = (const float*)d_in[3];
  const float* b1 = (const float*)d_in[4];
  const float* W2 = (const float*)d_in[5];
  const float* b2 = (const float*)d_in[6];
  const float* W3 = (const float*)d_in[7];
  const float* b3 = (const float*)d_in[8];
  float* y = (float*)d_out;

  char* ws = (char*)d_ws;
  float*  gacc    = (float*)ws;                 // 132 B (32 accum + cnt)
  bfrag*  w1f     = (bfrag*)(ws + 256);         // 524288 B
  bfrag*  w2f     = (bfrag*)(ws + 524544);      // 32768 B
  bfrag*  w3f     = (bfrag*)(ws + 557312);      // 32768 B
  float*  wgt     = (float*)(ws + 590080);      // 32768 B
  float4* routing = (float4*)(ws + 622848);     // 2097152 B
  char*   xbf     = ws + 2720000;               // 67108864 B (1024 x 64 KB)
  const bool use_xbf = ws_size >= (size_t)2720000 + 67108864;

  moe_prep<<<177, 256, 0, stream>>>(W1, W2, W3, wg, w1f, w2f, w3f, wgt, gacc);
  if (use_xbf) {
    moe_convert<<<1024, 1024, 0, stream>>>(x, xbf);
    moe_gate<<<1024, 1024, 0, stream>>>(x, bg, wgt, routing, gacc, y);
    moe_main<1><<<2048, 512, 0, stream>>>(x, xbf, b1, b2, b3, w1f, w2f, w3f, routing, y);
  } else {
    moe_gate<<<1024, 1024, 0, stream>>>(x, bg, wgt, routing, gacc, y);
    moe_main<0><<<2048, 512, 0, stream>>>(x, xbf, b1, b2, b3, w1f, w2f, w3f, routing, y);
  }
}

// Round 19
// 87.573 us; speedup vs baseline: 1.6928x; 1.6928x over previous
//
#include <hip/hip_runtime.h>

// ---------------------------------------------------------------------------
// Fully-fused Sparse-MMoE forward for MI355X (gfx950), v19 = v8/v16 verbatim.
// B=65536, D=512, E=8, H1=64, H2=32, O=64, T=2, K=2.
//
// FINAL: v8 is the measured best (87.3-87.9us across three runs).  The 18
// round search record: every structural escape regressed with a counter-
// verified cause -
//   occupancy push (v6,v9):   register-tier spills (WRITE 86-618 MB)
//   kernel splits (v4,v10):   x paid twice / scattered image writes
//   x-image detours (v11,v13,v17,v18): fr-liveness collapse, LDS-issue
//       serialization, or 536MB harness ws-fill dominating the replay
//   VALU/MFMA interleave (v14): live-set blowout -> spills
//   setprio (v15):            starves cross-block VALU/MFMA co-issue
//   prefetch hoist (v12):     gating-phase live-set past allocator limit
// v8's plateau is structural: exact-fp32 routing needs x in registers
// (fr[16]); with acc[4][4] that pins the 128-reg tier -> 2 blocks/CU ->
// barrier-phase serialization bounds the fused kernel at ~78us.
//
// moe_prep:  weight repack fp32 -> bf16 MFMA B-fragment order (+ wgt fp32
//            transpose copy, + gacc/cnt zeroing).
// moe_fused: 1024 blocks x 512 thr (8 waves = 8 experts), 64 tokens/block.
//            fp32 gating (scalar weight loads) -> top-2 -> bf16 MFMA MLP.
// ---------------------------------------------------------------------------

typedef short bfrag __attribute__((ext_vector_type(8)));   // 8 bf16 = 4 VGPRs
typedef float facc  __attribute__((ext_vector_type(4)));   // 4 f32 accum

#define MFMA16(a, b, c) __builtin_amdgcn_mfma_f32_16x16x32_bf16((a), (b), (c), 0, 0, 0)

__device__ __forceinline__ unsigned short bfbits(float f) {
  unsigned int u = __builtin_bit_cast(unsigned int, f);
  u += 0x7FFFu + ((u >> 16) & 1u);          // RNE
  return (unsigned short)(u >> 16);
}
__device__ __forceinline__ unsigned pack2(float a, float b) {
  return (unsigned)bfbits(a) | ((unsigned)bfbits(b) << 16);
}
__device__ __forceinline__ float bf2f(unsigned short s) {
  unsigned int u = ((unsigned int)s) << 16;
  return __builtin_bit_cast(float, u);
}

// LDS map (bytes):
//  [0,     65536) : gating partials [8w][64tok][16te] f32 (first 32 KB)
//                   -> X tile [64][512] bf16 pitch 1024, XOR ((r&7)<<4)
//                   -> H1/H2/Out wave-private chunks of 8 KB per expert
//  [65536, 70656) : G logits [64][20] f32
//  [70656, 72704) : rec [64 tok][2 task] float4 {g1,g2,e1,e2}
//  [72704, 72832) : lacc [32] f32 (imp t0|imp t1|load t0|load t1)
#define G_OFF   65536
#define R_OFF   70656
#define A_OFF   72704
#define SM_SIZE 72832

__global__ __launch_bounds__(512, 4) void moe_fused(
    const float* __restrict__ x,
    const float* __restrict__ b_gates,
    const float* __restrict__ wgt,      // [16 te][512 k] f32, te = t*8+e
    const float* __restrict__ b1,
    const float* __restrict__ b2,
    const float* __restrict__ b3,
    const bfrag* __restrict__ w1f,
    const bfrag* __restrict__ w2f,
    const bfrag* __restrict__ w3f,
    float* __restrict__ gacc_out,       // [32] + cnt at +32
    float* __restrict__ y)
{
  __shared__ alignas(16) char smem[SM_SIZE];
  const int tid = threadIdx.x;
  const int wave = tid >> 6, lane = tid & 63;
  const int q = lane & 15, g = lane >> 4;
  const int e = wave;                       // 8 waves = 8 experts
  const unsigned cb = (unsigned)e * 8192u;  // own H1/Out chunk

  if (tid < 32) ((float*)(smem + A_OFF))[tid] = 0.f;

  // ---------- load x: lane = token, wave = k-chunk [64w, 64w+64) ----------
  const float* src = x + (size_t)blockIdx.x * 64 * 512 + lane * 512 + wave * 64;
  float4 fr[16];
  #pragma unroll
  for (int j = 0; j < 16; ++j) fr[j] = ((const float4*)src)[j];

  // ---------- gating partial dots: exact fp32, wave-uniform scalar weights ----------
  {
    int wu = __builtin_amdgcn_readfirstlane(wave);
    const float* wbase = wgt + wu * 64;
    float* pp = (float*)(smem + wave * 4096 + lane * 64);
    #pragma unroll
    for (int te = 0; te < 16; ++te) {
      const float* wrow = wbase + te * 512;
      float a0 = 0.f, a1 = 0.f, a2 = 0.f, a3 = 0.f;
      #pragma unroll
      for (int j = 0; j < 16; ++j) {
        a0 = fmaf(fr[j].x, wrow[j * 4 + 0], a0);
        a1 = fmaf(fr[j].y, wrow[j * 4 + 1], a1);
        a2 = fmaf(fr[j].z, wrow[j * 4 + 2], a2);
        a3 = fmaf(fr[j].w, wrow[j * 4 + 3], a3);
      }
      pp[(te + lane) & 15] = (a0 + a1) + (a2 + a3);   // te-rotation: conflict-free
    }
  }
  __syncthreads();                                   // B0

  // ---------- reduce 8 wave-partials -> G logits ----------
  #pragma unroll
  for (int i0 = 0; i0 < 2; ++i0) {
    int i = i0 * 512 + tid;
    int tok = i >> 4, te = i & 15;
    const float* pb = (const float*)smem + tok * 16 + ((te + tok) & 15);
    float s = 0.f;
    #pragma unroll
    for (int w2 = 0; w2 < 8; ++w2) s += pb[w2 * 1024];
    ((float*)(smem + G_OFF))[tok * 20 + te] = s + b_gates[te];
  }
  __syncthreads();                                   // B1 (partials dead)

  // ---------- stage X tile from registers (overwrites partials region) ----------
  #pragma unroll
  for (int p = 0; p < 8; ++p) {
    uint4 v;
    v.x = pack2(fr[2 * p].x, fr[2 * p].y);
    v.y = pack2(fr[2 * p].z, fr[2 * p].w);
    v.z = pack2(fr[2 * p + 1].x, fr[2 * p + 1].y);
    v.w = pack2(fr[2 * p + 1].z, fr[2 * p + 1].w);
    unsigned byte = ((unsigned)(lane * 1024 + wave * 128 + p * 16)) ^ ((unsigned)(lane & 7) << 4);
    *(uint4*)(smem + byte) = v;
  }

  // ---------- top-2 + softmax -> LDS recs + imp/load atomics ----------
  if (tid < 128) {
    int tok = tid >> 1, task = tid & 1;
    const float* Gr = (const float*)(smem + G_OFF) + tok * 20 + task * 8;
    float l[8];
    #pragma unroll
    for (int ee = 0; ee < 8; ++ee) l[ee] = Gr[ee];
    float v1 = l[0]; int e1 = 0;
    #pragma unroll
    for (int ee = 1; ee < 8; ++ee) { if (l[ee] > v1) { v1 = l[ee]; e1 = ee; } }
    float v2 = -3.4e38f; int e2 = 0;
    #pragma unroll
    for (int ee = 0; ee < 8; ++ee) {
      if (ee != e1 && l[ee] > v2) { v2 = l[ee]; e2 = ee; }
    }
    float g1 = 1.f / (1.f + __expf(v2 - v1));
    float g2 = 1.f - g1;
    float4 rec;
    rec.x = g1; rec.y = g2;
    rec.z = __int_as_float(e1); rec.w = __int_as_float(e2);
    ((float4*)(smem + R_OFF))[tok * 2 + task] = rec;
    float* lacc = (float*)(smem + A_OFF);
    atomicAdd(lacc + task * 8 + e1, g1);
    atomicAdd(lacc + task * 8 + e2, g2);
    atomicAdd(lacc + 16 + task * 8 + e1, 1.f);
    atomicAdd(lacc + 16 + task * 8 + e2, 1.f);
  }
  __syncthreads();                                   // B2 (X staged)

  // ---------------- GEMM1: 64 tok x 64 h1, K=512, depth-1 B prefetch ------
  facc acc[4][4];
  #pragma unroll
  for (int m = 0; m < 4; ++m)
    #pragma unroll
    for (int n = 0; n < 4; ++n) acc[m][n] = (facc)0.f;

  const bfrag* w1e = w1f + e * 4096 + lane;
  bfrag Bc[4], Bn[4];
  #pragma unroll
  for (int n = 0; n < 4; ++n) Bc[n] = w1e[n * 64];
  #pragma unroll
  for (int ks = 0; ks < 16; ++ks) {
    if (ks < 15) {
      #pragma unroll
      for (int n = 0; n < 4; ++n) Bn[n] = w1e[(ks + 1) * 256 + n * 64];
    }
    #pragma unroll
    for (int m = 0; m < 4; ++m) {
      unsigned ba = ((unsigned)((m * 16 + q) * 1024 + ks * 64 + g * 16)) ^ ((unsigned)(q & 7) << 4);
      bfrag A = *(const bfrag*)(smem + ba);
      #pragma unroll
      for (int n = 0; n < 4; ++n) acc[m][n] = MFMA16(A, Bc[n], acc[m][n]);
    }
    if (ks < 15) {
      #pragma unroll
      for (int n = 0; n < 4; ++n) Bc[n] = Bn[n];
    }
  }

  // preload GEMM2 weights + bias (in flight across the barrier + H1 phase)
  bfrag W2r[4];
  #pragma unroll
  for (int i = 0; i < 4; ++i) W2r[i] = w2f[e * 256 + i * 64 + lane];
  float b2v0 = b2[e * 32 + q];
  float b2v1 = b2[e * 32 + 16 + q];
  __syncthreads();                                   // B3 (X dead)

  // ---------------- H1 -> own chunk (sigma: s = q*4+n) ----------------
  {
    float bv[4];
    #pragma unroll
    for (int n = 0; n < 4; ++n) bv[n] = b1[e * 64 + n * 16 + q];
    #pragma unroll
    for (int m = 0; m < 4; ++m) {
      #pragma unroll
      for (int j = 0; j < 4; ++j) {
        float v0 = fmaxf(acc[m][0][j] + bv[0], 0.f);
        float v1 = fmaxf(acc[m][1][j] + bv[1], 0.f);
        float v2 = fmaxf(acc[m][2][j] + bv[2], 0.f);
        float v3 = fmaxf(acc[m][3][j] + bv[3], 0.f);
        int rr = m * 16 + g * 4 + j;
        unsigned byte = cb + (((unsigned)(rr * 128 + q * 8)) ^ ((unsigned)(rr & 7) << 4));
        uint2 p; p.x = pack2(v0, v1); p.y = pack2(v2, v3);
        *(uint2*)(smem + byte) = p;
      }
    }
  }

  // ---------------- GEMM2: K=64 (sigma), N=32 ----------------
  {
    facc a2[4][2];
    #pragma unroll
    for (int m = 0; m < 4; ++m) { a2[m][0] = (facc)0.f; a2[m][1] = (facc)0.f; }
    #pragma unroll
    for (int ks = 0; ks < 2; ++ks) {
      #pragma unroll
      for (int m = 0; m < 4; ++m) {
        unsigned ba = cb + (((unsigned)((m * 16 + q) * 128 + ks * 64 + g * 16)) ^ ((unsigned)(q & 7) << 4));
        bfrag A = *(const bfrag*)(smem + ba);
        #pragma unroll
        for (int n = 0; n < 2; ++n) a2[m][n] = MFMA16(A, W2r[ks * 2 + n], a2[m][n]);
      }
    }
    // preload GEMM3 weights + bias
    bfrag W3r[4];
    #pragma unroll
    for (int n = 0; n < 4; ++n) W3r[n] = w3f[e * 256 + n * 64 + lane];
    float b3v[4];
    #pragma unroll
    for (int n = 0; n < 4; ++n) b3v[n] = b3[e * 64 + n * 16 + q];

    // H2 -> own chunk front (sigma2: s = q*2+n)
    #pragma unroll
    for (int m = 0; m < 4; ++m) {
      #pragma unroll
      for (int j = 0; j < 4; ++j) {
        float v0 = fmaxf(a2[m][0][j] + b2v0, 0.f);
        float v1 = fmaxf(a2[m][1][j] + b2v1, 0.f);
        int rr = m * 16 + g * 4 + j;
        unsigned byte = cb + (((unsigned)(rr * 64 + q * 4)) ^ ((unsigned)(rr & 7) << 4));
        *(unsigned int*)(smem + byte) = pack2(v0, v1);
      }
    }

    // ---------------- GEMM3: K=32 (sigma2), N=64 ----------------
    facc a3[4][4];
    #pragma unroll
    for (int m = 0; m < 4; ++m)
      #pragma unroll
      for (int n = 0; n < 4; ++n) a3[m][n] = (facc)0.f;
    #pragma unroll
    for (int m = 0; m < 4; ++m) {
      unsigned ba = cb + (((unsigned)((m * 16 + q) * 64 + g * 16)) ^ ((unsigned)(q & 7) << 4));
      bfrag A = *(const bfrag*)(smem + ba);
      #pragma unroll
      for (int n = 0; n < 4; ++n) a3[m][n] = MFMA16(A, W3r[n], a3[m][n]);
    }
    // Out -> full own chunk (sigma: s = q*4+n), after all H2 reads (in-order)
    #pragma unroll
    for (int m = 0; m < 4; ++m) {
      #pragma unroll
      for (int j = 0; j < 4; ++j) {
        float v0 = fmaxf(a3[m][0][j] + b3v[0], 0.f);
        float v1 = fmaxf(a3[m][1][j] + b3v[1], 0.f);
        float v2 = fmaxf(a3[m][2][j] + b3v[2], 0.f);
        float v3 = fmaxf(a3[m][3][j] + b3v[3], 0.f);
        int rr = m * 16 + g * 4 + j;
        unsigned byte = cb + (((unsigned)(rr * 128 + q * 8)) ^ ((unsigned)(rr & 7) << 4));
        uint2 p; p.x = pack2(v0, v1); p.y = pack2(v2, v3);
        *(uint2*)(smem + byte) = p;
      }
    }
  }
  __syncthreads();                                   // B4

  // ---------------- combine: LDS recs + weighted sum ----------------
  {
    int tsub = tid >> 4, u = tid & 15;
    const float4* recs = (const float4*)(smem + R_OFF);
    #pragma unroll
    for (int half = 0; half < 2; ++half) {
      int tok = tsub + half * 32;
      size_t trow = (size_t)blockIdx.x * 64 + tok;
      unsigned obyte = ((unsigned)(tok * 128 + u * 8)) ^ ((unsigned)(tok & 7) << 4);
      #pragma unroll
      for (int tt = 0; tt < 2; ++tt) {
        float4 rec = recs[tok * 2 + tt];
        float g1 = rec.x, g2 = rec.y;
        int e1 = __float_as_int(rec.z), e2 = __float_as_int(rec.w);
        uint2 o1 = *(const uint2*)(smem + e1 * 8192 + obyte);
        uint2 o2 = *(const uint2*)(smem + e2 * 8192 + obyte);
        unsigned short s1[4] = { (unsigned short)o1.x, (unsigned short)(o1.x >> 16),
                                 (unsigned short)o1.y, (unsigned short)(o1.y >> 16) };
        unsigned short s2[4] = { (unsigned short)o2.x, (unsigned short)(o2.x >> 16),
                                 (unsigned short)o2.y, (unsigned short)(o2.y >> 16) };
        float* yt = y + (size_t)tt * 4194304 + trow * 64;
        #pragma unroll
        for (int w = 0; w < 4; ++w) {
          // storage col s = 4u+w -> actual col c = w*16 + u
          yt[w * 16 + u] = g1 * bf2f(s1[w]) + g2 * bf2f(s2[w]);
        }
      }
    }
  }
  if (tid < 32) atomicAdd(gacc_out + tid, ((float*)(smem + A_OFF))[tid]);
  __syncthreads();                                   // B5: block's atomics drained

  // ---------- last-block-done: compute cv^2 loss in-kernel ----------
  if (tid == 0) {
    unsigned* cnt = (unsigned*)(gacc_out + 32);
    unsigned old = atomicAdd(cnt, 1u);
    if (old == gridDim.x - 1) {
      float loss = 0.f;
      #pragma unroll
      for (int a = 0; a < 4; ++a) {      // [imp t0][imp t1][load t0][load t1]
        float v[8]; float mm = 0.f;
        #pragma unroll
        for (int i = 0; i < 8; ++i) {
          v[i] = __hip_atomic_load(gacc_out + a * 8 + i, __ATOMIC_RELAXED,
                                   __HIP_MEMORY_SCOPE_AGENT);
          mm += v[i];
        }
        mm *= 0.125f;
        float var = 0.f;
        #pragma unroll
        for (int i = 0; i < 8; ++i) { float d = v[i] - mm; var += d * d; }
        loss += (var * (1.f / 7.f)) / (mm * mm + 1e-10f);
      }
      y[8388608] = 0.01f * loss;
    }
  }
}

// ============================ weight repack ================================
//  w1f: [E][16ks][4n][64lane]       B = W1[k][h], h = n*16+q
//  w2f: [E][2ks][2n][64]            K in H1-sigma order: h = (s&3)*16 + (s>>2)
//  w3f: [E][1][4n][64]              K in H2-sigma order: h = (s&1)*16 + (s>>1)
//  wgt: [16 te][512 k] f32          te = t*8+e (exact copy for fp32 gating)
//  also zeroes gacc[32] + done-counter
__global__ __launch_bounds__(256) void moe_prep(
    const float* __restrict__ W1, const float* __restrict__ W2,
    const float* __restrict__ W3, const float* __restrict__ wg,
    bfrag* __restrict__ w1f, bfrag* __restrict__ w2f,
    bfrag* __restrict__ w3f, float* __restrict__ wgt,
    float* __restrict__ gacc)
{
  int tid = blockIdx.x * 256 + threadIdx.x;
  bfrag o;
  if (tid < 32768) {
    int lane = tid & 63, nt = (tid >> 6) & 3, ks = (tid >> 8) & 15, e = tid >> 12;
    int q = lane & 15, g = lane >> 4;
    int hcol = nt * 16 + q;
    #pragma unroll
    for (int j = 0; j < 8; ++j) {
      int k = ks * 32 + g * 8 + j;
      o[j] = (short)bfbits(W1[((e * 512 + k) * 64) + hcol]);
    }
    w1f[tid] = o;
  } else if (tid < 34816) {
    int idx = tid - 32768;
    int lane = idx & 63, nt = (idx >> 6) & 1, ks = (idx >> 7) & 1, e = idx >> 8;
    int q = lane & 15, g = lane >> 4;
    int n = nt * 16 + q;
    #pragma unroll
    for (int j = 0; j < 8; ++j) {
      int s = ks * 32 + g * 8 + j;
      int hh = (s & 3) * 16 + (s >> 2);
      o[j] = (short)bfbits(W2[(e * 64 + hh) * 32 + n]);
    }
    w2f[idx] = o;
  } else if (tid < 36864) {
    int idx = tid - 34816;
    int lane = idx & 63, nt = (idx >> 6) & 3, e = idx >> 8;
    int q = lane & 15, g = lane >> 4;
    int ocol = nt * 16 + q;
    #pragma unroll
    for (int j = 0; j < 8; ++j) {
      int s = g * 8 + j;
      int hh = (s & 1) * 16 + (s >> 1);
      o[j] = (short)bfbits(W3[(e * 32 + hh) * 64 + ocol]);
    }
    w3f[idx] = o;
  } else if (tid < 45056) {
    int idx = tid - 36864;            // te = idx>>9, k = idx&511
    int te = idx >> 9, k = idx & 511;
    wgt[idx] = wg[(((te >> 3) * 512) + k) * 8 + (te & 7)];
  } else if (tid < 45089) {
    gacc[tid - 45056] = 0.f;          // gacc[0..31] + cnt (word 32)
  }
}

extern "C" void kernel_launch(void* const* d_in, const int* in_sizes, int n_in,
                              void* d_out, int out_size, void* d_ws, size_t ws_size,
                              hipStream_t stream) {
  const float* x  = (const float*)d_in[0];
  const float* wg = (const float*)d_in[1];
  const float* bg = (const float*)d_in[2];
  const float* W1 = (const float*)d_in[3];
  const float* b1 = (const float*)d_in[4];
  const float* W2 = (const float*)d_in[5];
  const float* b2 = (const float*)d_in[6];
  const float* W3 = (const float*)d_in[7];
  const float* b3 = (const float*)d_in[8];
  float* y = (float*)d_out;

  char* ws = (char*)d_ws;
  float*  gacc = (float*)ws;                 // 132 B (32 accum + cnt)
  bfrag*  w1f  = (bfrag*)(ws + 256);         // 524288 B
  bfrag*  w2f  = (bfrag*)(ws + 524544);      // 32768 B
  bfrag*  w3f  = (bfrag*)(ws + 557312);      // 32768 B
  float*  wgt  = (float*)(ws + 590080);      // 32768 B

  moe_prep<<<177, 256, 0, stream>>>(W1, W2, W3, wg, w1f, w2f, w3f, wgt, gacc);
  moe_fused<<<1024, 512, 0, stream>>>(x, bg, wgt, b1, b2, b3, w1f, w2f, w3f, gacc, y);
}